// Round 4
// baseline (301.102 us; speedup 1.0000x reference)
//
#include <hip/hip_runtime.h>
#include <hip/hip_bf16.h>

// out(2,40,40,40,64) f32 = conv3d(x, K5x5x5), self-connection folded into center tap.
// ws: Kb bf16 [125][kgrp8][o64][8] @ 0 (1 MB, L2-resident).
// conv: block = 320 positions (8 y-cols x 40 z, one x-plane), 4 waves, each 80x64.
// Per dx: stage input slab (12 y x 44 z x 64 ch) f32->bf16 into LDS transposed
// [ch-chunk 8][row = y*48+z] so all 25 (dy,dz) taps use immediate-offset ds_read_b128.
// z-stride 48: y-crossing jumps row by +9 (==1 mod 8) -> bank-conflict-free.

typedef __bf16 bf16x8 __attribute__((ext_vector_type(8)));
typedef float f32x4 __attribute__((ext_vector_type(4)));

#define COLCH 577                   // 12*48 = 576 chunks + 1 pad (577 % 8 == 1)
#define COLSTRIDE (COLCH * 16)      // 9232 B per ch-chunk column
#define LDS_BYTES (8 * COLSTRIDE)   // 73856 B

// ---------------- build_k: one thread per element ----------------
__global__ __launch_bounds__(256) void build_k(const float* __restrict__ lw,
                                               const float* __restrict__ wt,
                                               ushort* __restrict__ Kb) {
  int tid = blockIdx.x * 256 + threadIdx.x;   // 0 .. 511,999
  int j  = tid & 7;
  int o  = (tid >> 3) & 63;
  int kg = (tid >> 9) & 7;
  int l  = tid >> 12;
  int i  = kg * 8 + j;

  int ix = l / 25; int rem = l - ix * 25; int iy = rem / 5; int iz = rem - iy * 5;
  float cx = (float)(ix - 2), cy = (float)(iy - 2), cz = (float)(iz - 2);
  float r = sqrtf(cx * cx + cy * cy + cz * cz);

  float e[8];
  const float step = 2.5f / 9.0f;
  #pragma unroll
  for (int b = 0; b < 8; b++) {
    float diff = (r - (float)(b + 1) * step) / step;
    float den = fmaxf(1.0f - diff * diff, 1e-9f);
    e[b] = (fabsf(diff) < 1.0f) ? 1.14136f * expf(2.0f - 1.0f / den) : 0.0f;
  }
  float inv = (r > 0.0f) ? 1.0f / r : 0.0f;
  const float s3 = 1.7320508075688772f;
  float y1[3] = { s3 * cx * inv, s3 * cy * inv, s3 * cz * inv };
  const float a  = 0.17677669529663687f;     // 1/sqrt(2*MUL)
  const float a3 = 0.10206207261596575f;     // a/sqrt(3)

  auto wElem = [&](int c, int u, int w) -> float {
    const float* p = wt + c * 256 + u * 16 + w;
    float s = 0.f;
    #pragma unroll
    for (int b = 0; b < 8; b++) s += e[b] * p[b * 1024];
    return s * (1.0f / 125.0f);
  };

  float val;
  if (i < 16) {
    if (o < 16) {                       // Rss
      val = a * wElem(0, i, o);
    } else {                            // Rsv
      int om = o - 16; int w = om / 3, m = om - 3 * w;
      val = a * wElem(1, i, w) * y1[m];
    }
  } else {
    int im = i - 16; int u = im / 3, m = im - 3 * u;
    if (o < 16) {                       // Rvs
      val = a3 * wElem(3, u, o) * y1[m];
    } else {                            // Rvv (diagonal in m,n)
      int om = o - 16; int w = om / 3, nn = om - 3 * w;
      val = (m == nn) ? a * wElem(2, u, w) : 0.0f;
    }
  }
  if (l == 62) {   // center tap: fold self-connection (x @ Wl / sqrt(16))
    if (i < 16 && o < 16) {
      val += lw[i * 16 + o] * 0.25f;
    } else if (i >= 16 && o >= 16) {
      int im = i - 16, om = o - 16;
      int u = im / 3, m = im - 3 * u;
      int w = om / 3, nn = om - 3 * w;
      if (m == nn) val += lw[256 + u * 16 + w] * 0.25f;
    }
  }
  __hip_bfloat16 h = __float2bfloat16(val);
  Kb[tid] = *(ushort*)&h;
}

// ---------------- conv ----------------
__global__ __launch_bounds__(256, 2) void conv_mfma(const float* __restrict__ x,
                                                    const ushort* __restrict__ Kb_,
                                                    float* __restrict__ out) {
  const char* KbB = (const char*)Kb_;
  __shared__ __align__(16) char smem[LDS_BYTES];

  const int tid = threadIdx.x;
  const int lane = tid & 63;
  const int wv = tid >> 6;
  const int g = lane >> 4, ol = lane & 15;

  int bid = blockIdx.x;            // 400 = 2n x 40x x 5yg
  int yg = bid % 5; int t = bid / 5;
  int ox = t % 40; int n = t / 40;
  int y0 = yg * 8;
  int p0 = ((n * 40 + ox) * 40 + y0) * 40;

  // per-lane LDS byte base per m-tile (wave owns rows wv*80 .. wv*80+79)
  int lanebase[5];
  #pragma unroll
  for (int mt = 0; mt < 5; mt++) {
    int r = wv * 80 + mt * 16 + ol;
    int oyr = r / 40, oz = r - oyr * 40;
    lanebase[mt] = g * COLSTRIDE + (oyr * 48 + oz) * 16;
  }
  const int bbase = g * 1024 + ol * 16;   // B byte base within a tap slice

  f32x4 acc[5][4] = {};

  const float* xn = x + (size_t)n * 40 * 40 * 40 * 64;

  for (int dx = 0; dx < 5; dx++) {
    int ix = ox + dx - 2;
    if (ix < 0 || ix >= 40) continue;       // block-uniform: zero slab contributes nothing
    __syncthreads();                         // previous slab's reads complete
    const float* xpl = xn + (size_t)ix * 40 * 40 * 64;
    for (int it = 0; it < 17; it++) {
      int c = it * 256 + tid;
      if (c < 4224) {                        // 12 y * 44 z * 8 chunks
        int ch8 = c & 7;
        int rowsrc = c >> 3;                 // 0..527
        int yrel = rowsrc / 44;
        int zr = rowsrc - yrel * 44;
        int iy = y0 - 2 + yrel;
        int iz = zr - 2;
        int4 st = make_int4(0, 0, 0, 0);
        if (iy >= 0 && iy < 40 && iz >= 0 && iz < 40) {
          const float* src = xpl + ((size_t)iy * 40 + iz) * 64 + ch8 * 8;
          float4 f0 = ((const float4*)src)[0];
          float4 f1 = ((const float4*)src)[1];
          union { __hip_bfloat16 h[8]; int4 v4; } u;
          u.h[0] = __float2bfloat16(f0.x); u.h[1] = __float2bfloat16(f0.y);
          u.h[2] = __float2bfloat16(f0.z); u.h[3] = __float2bfloat16(f0.w);
          u.h[4] = __float2bfloat16(f1.x); u.h[5] = __float2bfloat16(f1.y);
          u.h[6] = __float2bfloat16(f1.z); u.h[7] = __float2bfloat16(f1.w);
          st = u.v4;
        }
        *(int4*)(smem + ch8 * COLSTRIDE + (yrel * 48 + zr) * 16) = st;
      }
    }
    __syncthreads();

    const char* kbdx = KbB + (size_t)dx * 25 * 8192 + bbase;
    #pragma unroll 1
    for (int dy = 0; dy < 5; dy++) {
      const int dyoff = dy * 48 * 16;
      const char* kbdy = kbdx + dy * 5 * 8192;
      #pragma unroll
      for (int dz = 0; dz < 5; dz++) {
        const int toff = dyoff + dz * 16;
        bf16x8 a[5][2], b[2][4];
        #pragma unroll
        for (int mt = 0; mt < 5; mt++)
          #pragma unroll
          for (int kc = 0; kc < 2; kc++)
            a[mt][kc] = *(const bf16x8*)(smem + lanebase[mt] + kc * (4 * COLSTRIDE) + toff);
        const char* kb = kbdy + dz * 8192;
        #pragma unroll
        for (int kc = 0; kc < 2; kc++)
          #pragma unroll
          for (int nt = 0; nt < 4; nt++)
            b[kc][nt] = *(const bf16x8*)(kb + kc * 4096 + nt * 256);
        #pragma unroll
        for (int kc = 0; kc < 2; kc++)
          #pragma unroll
          for (int nt = 0; nt < 4; nt++)
            #pragma unroll
            for (int mt = 0; mt < 5; mt++)
              acc[mt][nt] = __builtin_amdgcn_mfma_f32_16x16x32_bf16(a[mt][kc], b[kc][nt], acc[mt][nt], 0, 0, 0);
      }
    }
  }

  // ---------------- epilogue: LDS transpose -> contiguous float4 stores ----------------
  __syncthreads();                 // all waves done with slab reads
  float* sw = (float*)(smem + wv * (16 * 66 * 4));   // per-wave 16 x 66 f32
  #pragma unroll 1
  for (int mt = 0; mt < 5; mt++) {
    #pragma unroll
    for (int nt = 0; nt < 4; nt++)
      #pragma unroll
      for (int j = 0; j < 4; j++)
        sw[(g * 4 + j) * 66 + nt * 16 + ol] = acc[mt][nt][j];
    // same-wave ds_write -> ds_read ordering via lgkmcnt (compiler-inserted)
    float* outb = out + (size_t)(p0 + wv * 80 + mt * 16) * 64;
    #pragma unroll
    for (int i = 0; i < 4; i++) {
      int4 vv = *(int4*)&sw[(i * 4 + g) * 66 + ol * 4];
      ((int4*)outb)[i * 64 + lane] = vv;
    }
  }
}

extern "C" void kernel_launch(void* const* d_in, const int* in_sizes, int n_in,
                              void* d_out, int out_size, void* d_ws, size_t ws_size,
                              hipStream_t stream) {
  const float* x  = (const float*)d_in[0];
  const float* lw = (const float*)d_in[1];
  const float* wt = (const float*)d_in[2];
  float* out = (float*)d_out;
  ushort* Kb = (ushort*)d_ws;

  build_k<<<2000, 256, 0, stream>>>(lw, wt, Kb);
  conv_mfma<<<400, 256, 0, stream>>>(x, Kb, out);
}

// Round 8
// 288.784 us; speedup vs baseline: 1.0427x; 1.0427x over previous
//
#include <hip/hip_runtime.h>
#include <hip/hip_bf16.h>

// out(2,40,40,40,64) f32 = conv3d(x, K5x5x5) with self-connection folded into center tap.
// ws: xp bf16 [n2][x44][h2][y44][z44][c32] @0 (21.8MB, halo-padded, channel-halved),
//     Kb bf16 [125][kg8][o64][8] @XP_BYTES (1MB, L2-resident).
// conv: 128-thread (2-wave) blocks, M=160 (4 y-cols x 40 z, one x-plane), N=64/wave.
// K-split: loop h=0,1 over channel halves; per (h,dx) stage contiguous 22.5KB slab-half
// into LDS transposed [g4][row352] so all 25 (dy,dz) taps are immediate-offset ds_read_b128.
// 800 blocks, 24.6KB LDS -> 6 blocks/CU (12 waves); bijective XCD swizzle (800=8x100)
// gives each XCD 10 contiguous output planes (input working set ~3.5MB fits 4MB L2).

typedef __bf16 bf16x8 __attribute__((ext_vector_type(8)));
typedef float f32x4 __attribute__((ext_vector_type(4)));

#define XP_CHUNKS 1362944              // 16B chunks in xp
#define XP_BYTES  (XP_CHUNKS * 16)     // 21,807,104
#define COLU 385                       // 16B units per g-column (352 rows + pad)
#define COLSTRIDE (COLU * 16)
#define LDS_BYTES (4 * COLSTRIDE)      // 24,640 B

// ---------------- prep: pad_cast (blocks 0..5323) + build_k (blocks 5324..7323) ----------------
__global__ __launch_bounds__(256) void prep(const float* __restrict__ x,
                                            const float* __restrict__ lw,
                                            const float* __restrict__ wt,
                                            ushort* __restrict__ xp,
                                            ushort* __restrict__ Kb) {
  if (blockIdx.x < 5324) {
    int u = blockIdx.x * 256 + threadIdx.x;     // chunk id, 0..1,362,943
    int c8 = u & 3;
    int v = u >> 2;
    int zi = v % 44; int w = v / 44;
    int yi = w % 44; int w2 = w / 44;
    int h = w2 & 1; int w3 = w2 >> 1;
    int xi = w3 % 44; int n = w3 / 44;
    int4 st = make_int4(0, 0, 0, 0);
    if (xi >= 2 && xi < 42 && yi >= 2 && yi < 42 && zi >= 2 && zi < 42) {
      const float* src = x + ((((size_t)n * 40 + (xi - 2)) * 40 + (yi - 2)) * 40 + (zi - 2)) * 64
                           + h * 32 + c8 * 8;
      float4 f0 = ((const float4*)src)[0];
      float4 f1 = ((const float4*)src)[1];
      union { __hip_bfloat16 hh[8]; int4 v4; } uu;
      uu.hh[0] = __float2bfloat16(f0.x); uu.hh[1] = __float2bfloat16(f0.y);
      uu.hh[2] = __float2bfloat16(f0.z); uu.hh[3] = __float2bfloat16(f0.w);
      uu.hh[4] = __float2bfloat16(f1.x); uu.hh[5] = __float2bfloat16(f1.y);
      uu.hh[6] = __float2bfloat16(f1.z); uu.hh[7] = __float2bfloat16(f1.w);
      st = uu.v4;
    }
    ((int4*)xp)[u] = st;
  } else {
    int tid = (blockIdx.x - 5324) * 256 + threadIdx.x;   // 0 .. 511,999
    int j  = tid & 7;
    int o  = (tid >> 3) & 63;
    int kg = (tid >> 9) & 7;
    int l  = tid >> 12;
    int i  = kg * 8 + j;

    int ix = l / 25; int rem = l - ix * 25; int iy = rem / 5; int iz = rem - iy * 5;
    float cx = (float)(ix - 2), cy = (float)(iy - 2), cz = (float)(iz - 2);
    float r = sqrtf(cx * cx + cy * cy + cz * cz);

    float e[8];
    const float step = 2.5f / 9.0f;
    #pragma unroll
    for (int b = 0; b < 8; b++) {
      float diff = (r - (float)(b + 1) * step) / step;
      float den = fmaxf(1.0f - diff * diff, 1e-9f);
      e[b] = (fabsf(diff) < 1.0f) ? 1.14136f * expf(2.0f - 1.0f / den) : 0.0f;
    }
    float inv = (r > 0.0f) ? 1.0f / r : 0.0f;
    const float s3 = 1.7320508075688772f;
    float y1[3] = { s3 * cx * inv, s3 * cy * inv, s3 * cz * inv };
    const float a  = 0.17677669529663687f;     // 1/sqrt(2*MUL)
    const float a3 = 0.10206207261596575f;     // a/sqrt(3)

    auto wElem = [&](int c, int u_, int w_) -> float {
      const float* p = wt + c * 256 + u_ * 16 + w_;
      float s = 0.f;
      #pragma unroll
      for (int b = 0; b < 8; b++) s += e[b] * p[b * 1024];
      return s * (1.0f / 125.0f);
    };

    float val;
    if (i < 16) {
      if (o < 16) {                       // Rss
        val = a * wElem(0, i, o);
      } else {                            // Rsv
        int om = o - 16; int w_ = om / 3, m = om - 3 * w_;
        val = a * wElem(1, i, w_) * y1[m];
      }
    } else {
      int im = i - 16; int u_ = im / 3, m = im - 3 * u_;
      if (o < 16) {                       // Rvs
        val = a3 * wElem(3, u_, o) * y1[m];
      } else {                            // Rvv (diagonal in m,n)
        int om = o - 16; int w_ = om / 3, nn = om - 3 * w_;
        val = (m == nn) ? a * wElem(2, u_, w_) : 0.0f;
      }
    }
    if (l == 62) {   // center tap: fold self-connection (x @ Wl / sqrt(16))
      if (i < 16 && o < 16) {
        val += lw[i * 16 + o] * 0.25f;
      } else if (i >= 16 && o >= 16) {
        int im = i - 16, om = o - 16;
        int u_ = im / 3, m = im - 3 * u_;
        int w_ = om / 3, nn = om - 3 * w_;
        if (m == nn) val += lw[256 + u_ * 16 + w_] * 0.25f;
      }
    }
    __hip_bfloat16 hv = __float2bfloat16(val);
    Kb[tid] = *(ushort*)&hv;
  }
}

// ---------------- conv ----------------
__global__ __launch_bounds__(128, 3) void conv_mfma(const ushort* __restrict__ xp_,
                                                    const ushort* __restrict__ Kb_,
                                                    float* __restrict__ out) {
  const int4* xp4 = (const int4*)xp_;
  const char* KbB = (const char*)Kb_;
  __shared__ __align__(16) char smem[LDS_BYTES];

  const int tid = threadIdx.x;
  const int lane = tid & 63;
  const int wv = tid >> 6;
  const int g = lane >> 4, ol = lane & 15;

  // bijective XCD swizzle: 800 blocks = 8 XCDs x 100; each XCD gets 10 contiguous planes
  int bid = blockIdx.x;
  int wg = (bid & 7) * 100 + (bid >> 3);
  int yg = wg % 10; int t = wg / 10;
  int ox = t % 40; int n = t / 40;
  int y0 = yg * 4;
  int p0 = ((n * 40 + ox) * 40 + y0) * 40;

  // per-lane LDS byte base per m-tile (wave owns rows wv*80 .. wv*80+79)
  int lanebase[5];
  #pragma unroll
  for (int mt = 0; mt < 5; mt++) {
    int r = wv * 80 + mt * 16 + ol;
    int yo = r / 40, zo = r - yo * 40;
    lanebase[mt] = g * COLSTRIDE + (yo * 44 + zo) * 16;
  }
  const int bb = g * 1024 + ol * 16;     // B byte base within a tap slice

  f32x4 acc[5][4] = {};

  for (int h = 0; h < 2; h++) {
    for (int dx = 0; dx < 5; dx++) {
      // contiguous slab-half: (n, x'=ox+dx, h), rows y' in [y0, y0+8) x z' 44 -> 1408 chunks
      const int4* slab = xp4 + (size_t)((n * 44 + ox + dx) * 2 + h) * 7744 + y0 * 176;
      int4 v[11];
      #pragma unroll
      for (int it = 0; it < 11; it++)
        v[it] = slab[it * 128 + tid];
      __syncthreads();                    // previous slab's reads complete
      #pragma unroll
      for (int it = 0; it < 11; it++) {
        int c = it * 128 + tid;
        *(int4*)(smem + ((c & 3) * COLU + (c >> 2)) * 16) = v[it];
      }
      __syncthreads();

      const char* kb0 = KbB + (size_t)dx * 25 * 8192 + h * 4096 + bb;
      #pragma unroll 1
      for (int dy = 0; dy < 5; dy++) {
        const int rowoff = dy * 44 * 16;
        const char* kby = kb0 + dy * 5 * 8192;
        #pragma unroll
        for (int dz = 0; dz < 5; dz++) {
          bf16x8 a[5], b[4];
          #pragma unroll
          for (int mt = 0; mt < 5; mt++)
            a[mt] = *(const bf16x8*)(smem + lanebase[mt] + rowoff + dz * 16);
          #pragma unroll
          for (int nt = 0; nt < 4; nt++)
            b[nt] = *(const bf16x8*)(kby + dz * 8192 + nt * 256);
          #pragma unroll
          for (int nt = 0; nt < 4; nt++)
            #pragma unroll
            for (int mt = 0; mt < 5; mt++)
              acc[mt][nt] = __builtin_amdgcn_mfma_f32_16x16x32_bf16(a[mt], b[nt], acc[mt][nt], 0, 0, 0);
        }
      }
    }
  }

  // epilogue: direct dword stores (full 64B lines per instruction; no spills -> no amplification)
  #pragma unroll
  for (int mt = 0; mt < 5; mt++)
    #pragma unroll
    for (int nt = 0; nt < 4; nt++)
      #pragma unroll
      for (int j = 0; j < 4; j++) {
        int p = p0 + wv * 80 + mt * 16 + g * 4 + j;
        out[(size_t)p * 64 + nt * 16 + ol] = acc[mt][nt][j];
      }
}

extern "C" void kernel_launch(void* const* d_in, const int* in_sizes, int n_in,
                              void* d_out, int out_size, void* d_ws, size_t ws_size,
                              hipStream_t stream) {
  const float* x  = (const float*)d_in[0];
  const float* lw = (const float*)d_in[1];
  const float* wt = (const float*)d_in[2];
  float* out = (float*)d_out;
  ushort* xp = (ushort*)d_ws;
  ushort* Kb = (ushort*)((char*)d_ws + XP_BYTES);

  prep<<<7324, 256, 0, stream>>>(x, lw, wt, xp, Kb);
  conv_mfma<<<800, 128, 0, stream>>>(xp, Kb, out);
}

// Round 9
// 266.655 us; speedup vs baseline: 1.1292x; 1.0830x over previous
//
#include <hip/hip_runtime.h>
#include <hip/hip_bf16.h>

// out(2,40,40,40,64) f32 = conv3d(x, K5x5x5) with self-connection folded into center tap.
// ws: xp bf16 [n2][x44][h2][y44][z44][c32] @0 (21.8MB, halo-padded, channel-halved),
//     Kb bf16 [125][kg8][o64][8] @XP_BYTES (1MB, L2-resident).
// conv: 128-thread (2-wave) blocks, M=160 (4 y-cols x 40 z, one x-plane), N=64/wave.
// K-split: loop h=0,1 over channel halves; per (h,dx) stage contiguous 22.5KB slab-half
// into LDS transposed [g4][row352] so all 25 (dy,dz) taps are immediate-offset ds_read_b128.
// COLU=386 (== 2 mod 8): staging-write banks (2g+row) mod 8 cover each residue twice
// -> 2-way (free); reads contiguous per quarter-wave (free).
// launch_bounds(128,1): NO VGPR cap (R8's (128,3) capped at 84 -> acc spills -> 205MB writes).

typedef __bf16 bf16x8 __attribute__((ext_vector_type(8)));
typedef float f32x4 __attribute__((ext_vector_type(4)));

#define XP_CHUNKS 1362944              // 16B chunks in xp
#define XP_BYTES  (XP_CHUNKS * 16)     // 21,807,104
#define COLU 386                       // 16B units per g-column (352 rows + pad; 386%8==2)
#define COLSTRIDE (COLU * 16)
#define LDS_BYTES (4 * COLSTRIDE)      // 24,704 B

// ---------------- prep: pad_cast (blocks 0..5323) + build_k (blocks 5324..7323) ----------------
__global__ __launch_bounds__(256) void prep(const float* __restrict__ x,
                                            const float* __restrict__ lw,
                                            const float* __restrict__ wt,
                                            ushort* __restrict__ xp,
                                            ushort* __restrict__ Kb) {
  if (blockIdx.x < 5324) {
    int u = blockIdx.x * 256 + threadIdx.x;     // chunk id, 0..1,362,943
    int c8 = u & 3;
    int v = u >> 2;
    int zi = v % 44; int w = v / 44;
    int yi = w % 44; int w2 = w / 44;
    int h = w2 & 1; int w3 = w2 >> 1;
    int xi = w3 % 44; int n = w3 / 44;
    int4 st = make_int4(0, 0, 0, 0);
    if (xi >= 2 && xi < 42 && yi >= 2 && yi < 42 && zi >= 2 && zi < 42) {
      const float* src = x + ((((size_t)n * 40 + (xi - 2)) * 40 + (yi - 2)) * 40 + (zi - 2)) * 64
                           + h * 32 + c8 * 8;
      float4 f0 = ((const float4*)src)[0];
      float4 f1 = ((const float4*)src)[1];
      union { __hip_bfloat16 hh[8]; int4 v4; } uu;
      uu.hh[0] = __float2bfloat16(f0.x); uu.hh[1] = __float2bfloat16(f0.y);
      uu.hh[2] = __float2bfloat16(f0.z); uu.hh[3] = __float2bfloat16(f0.w);
      uu.hh[4] = __float2bfloat16(f1.x); uu.hh[5] = __float2bfloat16(f1.y);
      uu.hh[6] = __float2bfloat16(f1.z); uu.hh[7] = __float2bfloat16(f1.w);
      st = uu.v4;
    }
    ((int4*)xp)[u] = st;
  } else {
    int tid = (blockIdx.x - 5324) * 256 + threadIdx.x;   // 0 .. 511,999
    int j  = tid & 7;
    int o  = (tid >> 3) & 63;
    int kg = (tid >> 9) & 7;
    int l  = tid >> 12;
    int i  = kg * 8 + j;

    int ix = l / 25; int rem = l - ix * 25; int iy = rem / 5; int iz = rem - iy * 5;
    float cx = (float)(ix - 2), cy = (float)(iy - 2), cz = (float)(iz - 2);
    float r = sqrtf(cx * cx + cy * cy + cz * cz);

    float e[8];
    const float step = 2.5f / 9.0f;
    #pragma unroll
    for (int b = 0; b < 8; b++) {
      float diff = (r - (float)(b + 1) * step) / step;
      float den = fmaxf(1.0f - diff * diff, 1e-9f);
      e[b] = (fabsf(diff) < 1.0f) ? 1.14136f * expf(2.0f - 1.0f / den) : 0.0f;
    }
    float inv = (r > 0.0f) ? 1.0f / r : 0.0f;
    const float s3 = 1.7320508075688772f;
    float y1[3] = { s3 * cx * inv, s3 * cy * inv, s3 * cz * inv };
    const float a  = 0.17677669529663687f;     // 1/sqrt(2*MUL)
    const float a3 = 0.10206207261596575f;     // a/sqrt(3)

    auto wElem = [&](int c, int u_, int w_) -> float {
      const float* p = wt + c * 256 + u_ * 16 + w_;
      float s = 0.f;
      #pragma unroll
      for (int b = 0; b < 8; b++) s += e[b] * p[b * 1024];
      return s * (1.0f / 125.0f);
    };

    float val;
    if (i < 16) {
      if (o < 16) {                       // Rss
        val = a * wElem(0, i, o);
      } else {                            // Rsv
        int om = o - 16; int w_ = om / 3, m = om - 3 * w_;
        val = a * wElem(1, i, w_) * y1[m];
      }
    } else {
      int im = i - 16; int u_ = im / 3, m = im - 3 * u_;
      if (o < 16) {                       // Rvs
        val = a3 * wElem(3, u_, o) * y1[m];
      } else {                            // Rvv (diagonal in m,n)
        int om = o - 16; int w_ = om / 3, nn = om - 3 * w_;
        val = (m == nn) ? a * wElem(2, u_, w_) : 0.0f;
      }
    }
    if (l == 62) {   // center tap: fold self-connection (x @ Wl / sqrt(16))
      if (i < 16 && o < 16) {
        val += lw[i * 16 + o] * 0.25f;
      } else if (i >= 16 && o >= 16) {
        int im = i - 16, om = o - 16;
        int u_ = im / 3, m = im - 3 * u_;
        int w_ = om / 3, nn = om - 3 * w_;
        if (m == nn) val += lw[256 + u_ * 16 + w_] * 0.25f;
      }
    }
    __hip_bfloat16 hv = __float2bfloat16(val);
    Kb[tid] = *(ushort*)&hv;
  }
}

// ---------------- conv ----------------
__global__ __launch_bounds__(128, 1) void conv_mfma(const ushort* __restrict__ xp_,
                                                    const ushort* __restrict__ Kb_,
                                                    float* __restrict__ out) {
  const int4* xp4 = (const int4*)xp_;
  const char* KbB = (const char*)Kb_;
  __shared__ __align__(16) char smem[LDS_BYTES];

  const int tid = threadIdx.x;
  const int lane = tid & 63;
  const int wv = tid >> 6;
  const int g = lane >> 4, ol = lane & 15;

  // bijective XCD swizzle: 800 blocks = 8 XCDs x 100; each XCD gets 10 contiguous planes
  int bid = blockIdx.x;
  int wg = (bid & 7) * 100 + (bid >> 3);
  int yg = wg % 10; int t = wg / 10;
  int ox = t % 40; int n = t / 40;
  int y0 = yg * 4;
  int p0 = ((n * 40 + ox) * 40 + y0) * 40;

  // per-lane LDS byte base per m-tile (wave owns rows wv*80 .. wv*80+79)
  int lanebase[5];
  #pragma unroll
  for (int mt = 0; mt < 5; mt++) {
    int r = wv * 80 + mt * 16 + ol;
    int yo = r / 40, zo = r - yo * 40;
    lanebase[mt] = g * COLSTRIDE + (yo * 44 + zo) * 16;
  }
  const int bb = g * 1024 + ol * 16;     // B byte base within a tap slice

  f32x4 acc[5][4] = {};

  for (int h = 0; h < 2; h++) {
    for (int dx = 0; dx < 5; dx++) {
      // contiguous slab-half: (n, x'=ox+dx, h), rows y' in [y0, y0+8) x z' 44 -> 1408 chunks
      const int4* slab = xp4 + (size_t)((n * 44 + ox + dx) * 2 + h) * 7744 + y0 * 176;
      int4 v[11];
      #pragma unroll
      for (int it = 0; it < 11; it++)
        v[it] = slab[it * 128 + tid];
      __syncthreads();                    // previous slab's reads complete
      #pragma unroll
      for (int it = 0; it < 11; it++) {
        int c = it * 128 + tid;
        *(int4*)(smem + ((c & 3) * COLU + (c >> 2)) * 16) = v[it];
      }
      __syncthreads();

      const char* kb0 = KbB + (size_t)dx * 25 * 8192 + h * 4096 + bb;
      #pragma unroll 1
      for (int dy = 0; dy < 5; dy++) {
        const int rowoff = dy * 44 * 16;
        const char* kby = kb0 + dy * 5 * 8192;
        #pragma unroll
        for (int dz = 0; dz < 5; dz++) {
          bf16x8 a[5], b[4];
          #pragma unroll
          for (int mt = 0; mt < 5; mt++)
            a[mt] = *(const bf16x8*)(smem + lanebase[mt] + rowoff + dz * 16);
          #pragma unroll
          for (int nt = 0; nt < 4; nt++)
            b[nt] = *(const bf16x8*)(kby + dz * 8192 + nt * 256);
          #pragma unroll
          for (int nt = 0; nt < 4; nt++)
            #pragma unroll
            for (int mt = 0; mt < 5; mt++)
              acc[mt][nt] = __builtin_amdgcn_mfma_f32_16x16x32_bf16(a[mt], b[nt], acc[mt][nt], 0, 0, 0);
        }
      }
    }
  }

  // epilogue: direct dword stores (full 64B lines per instruction; no spills -> no amplification)
  #pragma unroll
  for (int mt = 0; mt < 5; mt++)
    #pragma unroll
    for (int nt = 0; nt < 4; nt++)
      #pragma unroll
      for (int j = 0; j < 4; j++) {
        int p = p0 + wv * 80 + mt * 16 + g * 4 + j;
        out[(size_t)p * 64 + nt * 16 + ol] = acc[mt][nt][j];
      }
}

extern "C" void kernel_launch(void* const* d_in, const int* in_sizes, int n_in,
                              void* d_out, int out_size, void* d_ws, size_t ws_size,
                              hipStream_t stream) {
  const float* x  = (const float*)d_in[0];
  const float* lw = (const float*)d_in[1];
  const float* wt = (const float*)d_in[2];
  float* out = (float*)d_out;
  ushort* xp = (ushort*)d_ws;
  ushort* Kb = (ushort*)((char*)d_ws + XP_BYTES);

  prep<<<7324, 256, 0, stream>>>(x, lw, wt, xp, Kb);
  conv_mfma<<<800, 128, 0, stream>>>(xp, Kb, out);
}